// Round 7
// baseline (253.778 us; speedup 1.0000x reference)
//
#include <hip/hip_runtime.h>
#include <hip/hip_bf16.h>
#include <math.h>

#define LRELU_ALPHA 0.2f

constexpr int B_ = 8;
constexpr int N_ = 2048;
constexpr int M_ = B_ * N_;      // 16384 rows total
constexpr int SEG = 32;          // ranks per segment
constexpr int NSEG = N_ / SEG;   // 64 segments per batch

// ---------------------------------------------------------------------------
// K1: h = text @ W (fp32) + fused scores s1,s2, eN0=exp(0.2*s2), eP0=exp(s2).
// 256 blocks x 256 threads. As row-major [64][132] (conflict-free staging +
// broadcast fragment reads); W full-K in LDS (R4: global-W = +33us, HBM-rate).
// Also zeroes segN/segP (for K2's atomics) and bcnt: 65536 threads cover
// 512*128 floats exactly (1 per thread per array).
// ---------------------------------------------------------------------------
__global__ __launch_bounds__(256) void k_gemm(const float* __restrict__ text,
                                              const float* __restrict__ W,
                                              const float* __restrict__ a,
                                              float* __restrict__ h,
                                              float* __restrict__ s1,
                                              float* __restrict__ s2,
                                              float* __restrict__ eN0,
                                              float* __restrict__ eP0,
                                              float* __restrict__ segN,
                                              float* __restrict__ segP,
                                              int* __restrict__ bcnt) {
    __shared__ __align__(16) float As[64 * 132];
    __shared__ __align__(16) float Ws[128 * 128];

    const int tid = threadIdx.x;
    const int blk = blockIdx.x;

    {   // zero the atomic accumulators (K2 runs strictly after K1).
        const int g = blk * 256 + tid;          // 0..65535 = 512*128 exactly
        segN[g] = 0.f;
        segP[g] = 0.f;
        if (blk == 0)
            for (int t = tid; t < B_ * NSEG; t += 256) bcnt[t] = 0;
    }

    const int r0  = blk * 64;
    const int cx  = tid & 15;
    const int ry  = tid >> 4;
    const int c0  = cx * 4;
    const int c1  = 64 + cx * 4;
    const int rr0 = ry * 4;

    for (int idx = tid; idx < 64 * 32; idx += 256) {
        int r = idx >> 5, k4 = (idx & 31) * 4;
        *(float4*)&As[r * 132 + k4] =
            *(const float4*)&text[(size_t)(r0 + r) * 128 + k4];
    }
    for (int idx = tid; idx < 128 * 32; idx += 256) {
        int k = idx >> 5, f4 = (idx & 31) * 4;
        *(float4*)&Ws[k * 128 + f4] = *(const float4*)&W[(size_t)k * 128 + f4];
    }
    __syncthreads();

    float acc[4][8];
#pragma unroll
    for (int i = 0; i < 4; ++i)
#pragma unroll
        for (int j = 0; j < 8; ++j) acc[i][j] = 0.f;

#pragma unroll 2
    for (int k0 = 0; k0 < 128; k0 += 4) {
        float4 av[4];
#pragma unroll
        for (int i = 0; i < 4; ++i)
            av[i] = *(const float4*)&As[(rr0 + i) * 132 + k0];
#pragma unroll
        for (int kk = 0; kk < 4; ++kk) {
            float4 w0 = *(const float4*)&Ws[(k0 + kk) * 128 + c0];
            float4 w1 = *(const float4*)&Ws[(k0 + kk) * 128 + c1];
#pragma unroll
            for (int i = 0; i < 4; ++i) {
                const float avv = (kk == 0) ? av[i].x : (kk == 1) ? av[i].y
                                : (kk == 2) ? av[i].z : av[i].w;
                acc[i][0] += avv * w0.x; acc[i][1] += avv * w0.y;
                acc[i][2] += avv * w0.z; acc[i][3] += avv * w0.w;
                acc[i][4] += avv * w1.x; acc[i][5] += avv * w1.y;
                acc[i][6] += avv * w1.z; acc[i][7] += avv * w1.w;
            }
        }
    }

    float4 a1lo = *(const float4*)&a[c0];
    float4 a1hi = *(const float4*)&a[c1];
    float4 a2lo = *(const float4*)&a[128 + c0];
    float4 a2hi = *(const float4*)&a[128 + c1];

#pragma unroll
    for (int i = 0; i < 4; ++i) {
        const int row = r0 + rr0 + i;
        float4 o0 = {acc[i][0], acc[i][1], acc[i][2], acc[i][3]};
        float4 o1 = {acc[i][4], acc[i][5], acc[i][6], acc[i][7]};
        *(float4*)&h[(size_t)row * 128 + c0] = o0;
        *(float4*)&h[(size_t)row * 128 + c1] = o1;

        float p1 = o0.x*a1lo.x + o0.y*a1lo.y + o0.z*a1lo.z + o0.w*a1lo.w
                 + o1.x*a1hi.x + o1.y*a1hi.y + o1.z*a1hi.z + o1.w*a1hi.w;
        float p2 = o0.x*a2lo.x + o0.y*a2lo.y + o0.z*a2lo.z + o0.w*a2lo.w
                 + o1.x*a2hi.x + o1.y*a2hi.y + o1.z*a2hi.z + o1.w*a2hi.w;
#pragma unroll
        for (int off = 8; off >= 1; off >>= 1) {
            p1 += __shfl_xor(p1, off);
            p2 += __shfl_xor(p2, off);
        }
        if (cx == 0) {
            s1[row] = p1;
            s2[row] = p2;
            eN0[row] = expf(LRELU_ALPHA * p2);
            eP0[row] = expf(p2);
        }
    }
}

// ---------------------------------------------------------------------------
// K2: counting rank + buckets + (NEW, was K3) atomic segment sums.
// Phase 2 exploits that this block owns 64 CONTIGUOUS rows: the h gather is
// a coalesced 32KB sequential read (old K3 gathered scattered sorted rows),
// then atomicAdd into segN/segP[seg(tm)] — exactly 32 adds per cell.
// ---------------------------------------------------------------------------
__global__ __launch_bounds__(512) void k_rank(const float* __restrict__ s2,
                                              const float* __restrict__ eN0,
                                              const float* __restrict__ eP0,
                                              const float* __restrict__ s1,
                                              const float* __restrict__ h,
                                              int* __restrict__ perm,
                                              float* __restrict__ eNs,
                                              float* __restrict__ ePs,
                                              float* __restrict__ ZN,
                                              float* __restrict__ ZP,
                                              float* __restrict__ segN,
                                              float* __restrict__ segP,
                                              int* __restrict__ bcnt,
                                              int* __restrict__ bucket) {
    __shared__ float ls2[2048], leN[2048], leP[2048];
    __shared__ int   redc[512], redm[512];
    __shared__ float redn[512], redp[512];
    __shared__ int   tmL[64];

    const int b  = blockIdx.x >> 5;
    const int eb = blockIdx.x & 31;
    const int tid = threadIdx.x;
    const int e = tid & 63;
    const int c = tid >> 6;            // chunk 0..7

    {
        const float4* g2 = (const float4*)(s2  + b * 2048);
        const float4* gn = (const float4*)(eN0 + b * 2048);
        const float4* gp = (const float4*)(eP0 + b * 2048);
        ((float4*)ls2)[tid] = g2[tid];
        ((float4*)leN)[tid] = gn[tid];
        ((float4*)leP)[tid] = gp[tid];
    }
    __syncthreads();

    const int i  = eb * 64 + e;
    const int gi = b * 2048 + i;
    const float myS2 = ls2[i];
    const float thr  = -s1[gi];

    int cnt = 0, mr = 0;
    float sn = 0.f, sp = 0.f;
    const int j0 = c * 256;
#pragma unroll 4
    for (int j = j0; j < j0 + 256; j += 4) {
        float4 v  = *(const float4*)&ls2[j];
        float4 en = *(const float4*)&leN[j];
        float4 ep = *(const float4*)&leP[j];
#define PROC(vv, ee, pp, jj)                                             \
        { bool le = (vv) <= thr;                                         \
          cnt += le ? 1 : 0;                                             \
          sn  += le ? (ee) : 0.f;                                        \
          sp  += le ? 0.f : (pp);                                        \
          mr  += ((vv) < myS2 || ((vv) == myS2 && (jj) < i)) ? 1 : 0; }
        PROC(v.x, en.x, ep.x, j + 0)
        PROC(v.y, en.y, ep.y, j + 1)
        PROC(v.z, en.z, ep.z, j + 2)
        PROC(v.w, en.w, ep.w, j + 3)
#undef PROC
    }
    redc[tid] = cnt; redm[tid] = mr; redn[tid] = sn; redp[tid] = sp;
    __syncthreads();
    if (c == 0) {
        int tc = 0, tm = 0; float tn = 0.f, tp = 0.f;
#pragma unroll
        for (int cc = 0; cc < 8; ++cc) {
            tc += redc[cc * 64 + e];
            tm += redm[cc * 64 + e];
            tn += redn[cc * 64 + e];
            tp += redp[cc * 64 + e];
        }
        perm[b * 2048 + tm] = i;
        eNs [b * 2048 + tm] = leN[i];
        ePs [b * 2048 + tm] = leP[i];
        ZN[gi] = tn;
        ZP[gi] = tp;
        tmL[e] = tm;                               // sorted position, [0,2047]
        const int seg = min(tc >> 5, NSEG - 1);    // rank-segment for emit
        const int pos = atomicAdd(&bcnt[b * NSEG + seg], 1);
        if (pos < 2048)
            bucket[(b * NSEG + seg) * 2048 + pos] = i | (tc << 11);
    }
    __syncthreads();

    // Phase 2 (was K3): coalesced h gather of OWN 64 rows + atomic seg sums.
    {
        const int f  = tid & 127;
        const int q  = tid >> 7;                   // 0..3
#pragma unroll 4
        for (int it = 0; it < 16; ++it) {
            const int rl = it * 4 + q;             // 0..63
            const int ii = eb * 64 + rl;
            const int sg = tmL[rl] >> 5;           // [0,63] (tm<2048)
            const float hvv = h[(size_t)(b * 2048 + ii) * 128 + f];
            atomicAdd(&segN[(b * NSEG + sg) * 128 + f], leN[ii] * hvv);
            atomicAdd(&segP[(b * NSEG + sg) * 128 + f], leP[ii] * hvv);
        }
    }
}

// ---------------------------------------------------------------------------
// K3': segment-local prefix/suffix vectors in LDS (fp32) + direct output
// emission. 256 threads: half-block hf=0 does {prefix base, forward scan},
// hf=1 does {suffix base, backward scan} CONCURRENTLY (halves both serial
// spans vs R6); emit handles 2 rows per iteration (t = t0 + hf).
// ---------------------------------------------------------------------------
__global__ __launch_bounds__(256) void k_scanout(
    const float* __restrict__ h, const int* __restrict__ perm,
    const float* __restrict__ eNs, const float* __restrict__ ePs,
    const float* __restrict__ s1,
    const float* __restrict__ ZN, const float* __restrict__ ZP,
    const float* __restrict__ segN, const float* __restrict__ segP,
    const int* __restrict__ bcnt, const int* __restrict__ bucket,
    float* __restrict__ out) {

    __shared__ float anL[(SEG + 1) * 128];
    __shared__ float apL[(SEG + 1) * 128];

    const int blk = blockIdx.x;
    const int b = blk >> 6, s = blk & 63;
    const int tid = threadIdx.x;
    const int f  = tid & 127;
    const int hf = tid >> 7;

    // Gather this segment's 32 sorted rows (unrolled: all loads in flight).
    const int rr0 = b * 2048 + s * SEG;
    const float* es = hf ? ePs : eNs;
    int pm[SEG];
#pragma unroll
    for (int r = 0; r < SEG; ++r) pm[r] = perm[rr0 + r];
    float ev[SEG];
#pragma unroll
    for (int r = 0; r < SEG; ++r) ev[r] = es[rr0 + r];
    float hv[SEG];
#pragma unroll
    for (int r = 0; r < SEG; ++r)
        hv[r] = h[(size_t)(b * 2048 + pm[r]) * 128 + f];

    if (hf == 0) {
        float an = 0.f;
        for (int ss = 0; ss < s; ++ss) an += segN[(b * NSEG + ss) * 128 + f];
#pragma unroll
        for (int r = 0; r < SEG; ++r) {
            anL[r * 128 + f] = an;
            an += ev[r] * hv[r];
        }
        anL[SEG * 128 + f] = an;
    } else {
        float ap = 0.f;
        for (int ss = s + 1; ss < NSEG; ++ss) ap += segP[(b * NSEG + ss) * 128 + f];
        apL[SEG * 128 + f] = ap;
#pragma unroll
        for (int r = SEG - 1; r >= 0; --r) {
            ap += ev[r] * hv[r];
            apL[r * 128 + f] = ap;
        }
    }
    __syncthreads();

    // Emit output rows bucketed to this segment; 2 rows per iteration.
    const int m = min(bcnt[b * NSEG + s], 2048);
    for (int t0 = 0; t0 < m; t0 += 2) {
        const int t = t0 + hf;
        if (t < m) {
            const int packed = bucket[(b * NSEG + s) * 2048 + t];
            const int il = packed & 2047;
            const int tc = packed >> 11;
            const int gi = b * 2048 + il;
            const int pl = tc - s * SEG;        // in [0,32]
            const float s1v = s1[gi];
            const float E1 = expf(s1v);
            const float E2 = expf(LRELU_ALPHA * s1v);
            const float Z  = E1 * ZP[gi] + E2 * ZN[gi];
            const float hp = (E1 * apL[pl * 128 + f]
                            + E2 * anL[pl * 128 + f]) / Z;
            const float x  = hp + LRELU_ALPHA * h[(size_t)gi * 128 + f];
            out[(size_t)gi * 128 + f] = (x > 0.f) ? x : expm1f(x);
        }
    }
}

// ---------------------------------------------------------------------------
extern "C" void kernel_launch(void* const* d_in, const int* in_sizes, int n_in,
                              void* d_out, int out_size, void* d_ws, size_t ws_size,
                              hipStream_t stream) {
    const float* text = (const float*)d_in[0];
    // d_in[1] = adj : all-ones, unused by the reference math -> never read.
    const float* W = (const float*)d_in[2];
    const float* a = (const float*)d_in[3];
    float* out = (float*)d_out;

    float* p = (float*)d_ws;
    float* h    = p; p += (size_t)M_ * 128;
    float* s1   = p; p += M_;
    float* s2   = p; p += M_;
    float* eN0  = p; p += M_;
    float* eP0  = p; p += M_;
    int*   perm = (int*)p; p += M_;
    float* eNs  = p; p += M_;
    float* ePs  = p; p += M_;
    float* ZN   = p; p += M_;
    float* ZP   = p; p += M_;
    float* segN = p; p += B_ * NSEG * 128;
    float* segP = p; p += B_ * NSEG * 128;
    int*   bcnt = (int*)p; p += B_ * NSEG;
    int*   bucket = (int*)p; p += (size_t)B_ * NSEG * 2048;

    hipLaunchKernelGGL(k_gemm,   dim3(M_ / 64),   dim3(256), 0, stream,
                       text, W, a, h, s1, s2, eN0, eP0, segN, segP, bcnt);
    hipLaunchKernelGGL(k_rank,   dim3(B_ * 32),   dim3(512), 0, stream,
                       s2, eN0, eP0, s1, h, perm, eNs, ePs, ZN, ZP,
                       segN, segP, bcnt, bucket);
    hipLaunchKernelGGL(k_scanout, dim3(B_ * NSEG), dim3(256), 0, stream,
                       h, perm, eNs, ePs, s1, ZN, ZP, segN, segP,
                       bcnt, bucket, out);
}

// Round 9
// 232.454 us; speedup vs baseline: 1.0917x; 1.0917x over previous
//
#include <hip/hip_runtime.h>
#include <hip/hip_bf16.h>
#include <math.h>

#define LRELU_ALPHA 0.2f

constexpr int B_ = 8;
constexpr int N_ = 2048;
constexpr int M_ = B_ * N_;      // 16384 rows total
constexpr int SEG = 32;          // ranks per segment for the vector scans
constexpr int NSEG = N_ / SEG;   // 64 segments per batch

// ---------------------------------------------------------------------------
// K1: h = text @ W (fp32), fused epilogue: s1 = h·a1, s2 = h·a2,
//     eN0 = exp(0.2*s2), eP0 = exp(s2).   (R2 champion version, verbatim.)
// ---------------------------------------------------------------------------
__global__ __launch_bounds__(256) void k_gemm(const float* __restrict__ text,
                                              const float* __restrict__ W,
                                              const float* __restrict__ a,
                                              float* __restrict__ h,
                                              float* __restrict__ s1,
                                              float* __restrict__ s2,
                                              float* __restrict__ eN0,
                                              float* __restrict__ eP0) {
    __shared__ __align__(16) float Ast[64 * 68];   // [k][r], stride 68
    __shared__ __align__(16) float Ws[64 * 128];   // [k][f]

    const int tid = threadIdx.x;
    const int r0  = blockIdx.x * 64;
    const int cx  = tid & 15;
    const int ry  = tid >> 4;
    const int c0  = cx * 4;
    const int c1  = 64 + cx * 4;
    const int rr0 = ry * 4;

    float acc[4][8];
#pragma unroll
    for (int i = 0; i < 4; ++i)
#pragma unroll
        for (int j = 0; j < 8; ++j) acc[i][j] = 0.f;

    for (int kk = 0; kk < 128; kk += 64) {
        for (int idx = tid; idx < 64 * 16; idx += 256) {
            int r = idx >> 4, k4 = (idx & 15) * 4;
            float4 v = *(const float4*)&text[(size_t)(r0 + r) * 128 + kk + k4];
            Ast[(k4 + 0) * 68 + r] = v.x;
            Ast[(k4 + 1) * 68 + r] = v.y;
            Ast[(k4 + 2) * 68 + r] = v.z;
            Ast[(k4 + 3) * 68 + r] = v.w;
        }
        for (int idx = tid; idx < 64 * 32; idx += 256) {
            int k = idx >> 5, f4 = (idx & 31) * 4;
            *(float4*)&Ws[k * 128 + f4] =
                *(const float4*)&W[(size_t)(kk + k) * 128 + f4];
        }
        __syncthreads();
#pragma unroll 16
        for (int k = 0; k < 64; ++k) {
            float4 av = *(const float4*)&Ast[k * 68 + rr0];
            float4 w0 = *(const float4*)&Ws[k * 128 + c0];
            float4 w1 = *(const float4*)&Ws[k * 128 + c1];
            const float avv[4] = {av.x, av.y, av.z, av.w};
#pragma unroll
            for (int i = 0; i < 4; ++i) {
                acc[i][0] += avv[i] * w0.x; acc[i][1] += avv[i] * w0.y;
                acc[i][2] += avv[i] * w0.z; acc[i][3] += avv[i] * w0.w;
                acc[i][4] += avv[i] * w1.x; acc[i][5] += avv[i] * w1.y;
                acc[i][6] += avv[i] * w1.z; acc[i][7] += avv[i] * w1.w;
            }
        }
        __syncthreads();
    }

    float4 a1lo = *(const float4*)&a[c0];
    float4 a1hi = *(const float4*)&a[c1];
    float4 a2lo = *(const float4*)&a[128 + c0];
    float4 a2hi = *(const float4*)&a[128 + c1];

#pragma unroll
    for (int i = 0; i < 4; ++i) {
        const int row = r0 + rr0 + i;
        float4 o0 = {acc[i][0], acc[i][1], acc[i][2], acc[i][3]};
        float4 o1 = {acc[i][4], acc[i][5], acc[i][6], acc[i][7]};
        *(float4*)&h[(size_t)row * 128 + c0] = o0;
        *(float4*)&h[(size_t)row * 128 + c1] = o1;

        float p1 = o0.x*a1lo.x + o0.y*a1lo.y + o0.z*a1lo.z + o0.w*a1lo.w
                 + o1.x*a1hi.x + o1.y*a1hi.y + o1.z*a1hi.z + o1.w*a1hi.w;
        float p2 = o0.x*a2lo.x + o0.y*a2lo.y + o0.z*a2lo.z + o0.w*a2lo.w
                 + o1.x*a2hi.x + o1.y*a2hi.y + o1.z*a2hi.z + o1.w*a2hi.w;
#pragma unroll
        for (int off = 8; off >= 1; off >>= 1) {
            p1 += __shfl_xor(p1, off);
            p2 += __shfl_xor(p2, off);
        }
        if (cx == 0) {
            s1[row] = p1;
            s2[row] = p2;
            eN0[row] = expf(LRELU_ALPHA * p2);
            eP0[row] = expf(p2);
        }
    }
}

// ---------------------------------------------------------------------------
// K2: counting-rank kernel (R2 champion, verbatim).
// ---------------------------------------------------------------------------
__global__ __launch_bounds__(512) void k_rank(const float* __restrict__ s2,
                                              const float* __restrict__ eN0,
                                              const float* __restrict__ eP0,
                                              const float* __restrict__ s1,
                                              int* __restrict__ perm,
                                              float* __restrict__ eNs,
                                              float* __restrict__ ePs,
                                              int* __restrict__ rank,
                                              float* __restrict__ ZN,
                                              float* __restrict__ ZP) {
    __shared__ float ls2[2048], leN[2048], leP[2048];
    __shared__ int   redc[512], redm[512];
    __shared__ float redn[512], redp[512];

    const int b  = blockIdx.x >> 5;
    const int eb = blockIdx.x & 31;
    const int tid = threadIdx.x;
    const int e = tid & 63;
    const int c = tid >> 6;            // chunk 0..7

    {
        const float4* g2 = (const float4*)(s2  + b * 2048);
        const float4* gn = (const float4*)(eN0 + b * 2048);
        const float4* gp = (const float4*)(eP0 + b * 2048);
        ((float4*)ls2)[tid] = g2[tid];
        ((float4*)leN)[tid] = gn[tid];
        ((float4*)leP)[tid] = gp[tid];
    }
    __syncthreads();

    const int i  = eb * 64 + e;
    const int gi = b * 2048 + i;
    const float myS2 = ls2[i];
    const float thr  = -s1[gi];

    int cnt = 0, mr = 0;
    float sn = 0.f, sp = 0.f;
    const int j0 = c * 256;
#pragma unroll 4
    for (int j = j0; j < j0 + 256; j += 4) {
        float4 v  = *(const float4*)&ls2[j];
        float4 en = *(const float4*)&leN[j];
        float4 ep = *(const float4*)&leP[j];
#define PROC(vv, ee, pp, jj)                                             \
        { bool le = (vv) <= thr;                                         \
          cnt += le ? 1 : 0;                                             \
          sn  += le ? (ee) : 0.f;                                        \
          sp  += le ? 0.f : (pp);                                        \
          mr  += ((vv) < myS2 || ((vv) == myS2 && (jj) < i)) ? 1 : 0; }
        PROC(v.x, en.x, ep.x, j + 0)
        PROC(v.y, en.y, ep.y, j + 1)
        PROC(v.z, en.z, ep.z, j + 2)
        PROC(v.w, en.w, ep.w, j + 3)
#undef PROC
    }
    redc[tid] = cnt; redm[tid] = mr; redn[tid] = sn; redp[tid] = sp;
    __syncthreads();
    if (c == 0) {
        int tc = 0, tm = 0; float tn = 0.f, tp = 0.f;
#pragma unroll
        for (int cc = 0; cc < 8; ++cc) {
            tc += redc[cc * 64 + e];
            tm += redm[cc * 64 + e];
            tn += redn[cc * 64 + e];
            tp += redp[cc * 64 + e];
        }
        perm[b * 2048 + tm] = i;
        eNs [b * 2048 + tm] = leN[i];
        ePs [b * 2048 + tm] = leP[i];
        rank[gi] = tc;
        ZN[gi] = tn;
        ZP[gi] = tp;
    }
}

// ---------------------------------------------------------------------------
// K3: per (batch, segment) sums. CHANGE vs R2: gather fully unrolled so all
// 32 perm loads, then all 32 h-row loads, are independently in flight
// (was: partially-unrolled loop with per-iteration dependent load chains).
// ---------------------------------------------------------------------------
__global__ __launch_bounds__(128) void k_segsum(const float* __restrict__ h,
                                                const int* __restrict__ perm,
                                                const float* __restrict__ eNs,
                                                const float* __restrict__ ePs,
                                                float* __restrict__ segN,
                                                float* __restrict__ segP) {
    const int blk = blockIdx.x;
    const int b = blk >> 6, s = blk & 63;
    const int f = threadIdx.x;
    const int rr0 = b * 2048 + s * SEG;

    int pm[SEG];
#pragma unroll
    for (int r = 0; r < SEG; ++r) pm[r] = perm[rr0 + r];
    float hv[SEG];
#pragma unroll
    for (int r = 0; r < SEG; ++r)
        hv[r] = h[(size_t)(b * 2048 + pm[r]) * 128 + f];

    float an = 0.f, ap = 0.f;
#pragma unroll
    for (int r = 0; r < SEG; ++r) {
        an += eNs[rr0 + r] * hv[r];
        ap += ePs[rr0 + r] * hv[r];
    }
    segN[blk * 128 + f] = an;
    segP[blk * 128 + f] = ap;
}

// ---------------------------------------------------------------------------
// K4: prefix/suffix arrays, bf16 (fp32 accum), fwd/bwd in separate blocks
// (R2 structure). CHANGE vs R2: pm/ev/hv gathered into registers up front
// (all loads in flight) instead of per-scan-step dependent loads.
// ---------------------------------------------------------------------------
__global__ __launch_bounds__(128) void k_prefix(const float* __restrict__ h,
                                                const int* __restrict__ perm,
                                                const float* __restrict__ eNs,
                                                const float* __restrict__ ePs,
                                                const float* __restrict__ segN,
                                                const float* __restrict__ segP,
                                                __hip_bfloat16* __restrict__ Pre,
                                                __hip_bfloat16* __restrict__ Suf) {
    const int blk  = blockIdx.x;
    const int dir  = blk & 1;
    const int task = blk >> 1;
    const int b = task >> 6, s = task & 63;
    const int f = threadIdx.x;
    const int rbase = s * SEG;
    const int rr0 = b * 2048 + rbase;

    // Up-front gathers: perm -> h rows -> e weights, each batch independent.
    const float* es = dir ? ePs : eNs;
    int pm[SEG];
#pragma unroll
    for (int r = 0; r < SEG; ++r) pm[r] = perm[rr0 + r];
    float ev[SEG];
#pragma unroll
    for (int r = 0; r < SEG; ++r) ev[r] = es[rr0 + r];
    float hv[SEG];
#pragma unroll
    for (int r = 0; r < SEG; ++r)
        hv[r] = h[(size_t)(b * 2048 + pm[r]) * 128 + f];

    if (dir == 0) {
        float an = 0.f;
        for (int ss = 0; ss < s; ++ss) an += segN[(b * NSEG + ss) * 128 + f];
#pragma unroll
        for (int r = 0; r < SEG; ++r) {
            Pre[(size_t)(b * 2049 + rbase + r) * 128 + f] = __float2bfloat16(an);
            an += ev[r] * hv[r];
        }
        if (s == NSEG - 1)
            Pre[(size_t)(b * 2049 + 2048) * 128 + f] = __float2bfloat16(an);
    } else {
        float ap = 0.f;
        for (int ss = s + 1; ss < NSEG; ++ss) ap += segP[(b * NSEG + ss) * 128 + f];
#pragma unroll
        for (int r = SEG - 1; r >= 0; --r) {
            ap += ev[r] * hv[r];
            Suf[(size_t)(b * 2049 + rbase + r) * 128 + f] = __float2bfloat16(ap);
        }
        if (s == NSEG - 1)
            Suf[(size_t)(b * 2049 + 2048) * 128 + f] = __float2bfloat16(0.f);
    }
}

// ---------------------------------------------------------------------------
// K5: out = elu(h' + 0.2 h) (R2 champion, verbatim).
// ---------------------------------------------------------------------------
__global__ __launch_bounds__(256) void k_out(const float* __restrict__ h,
                                             const float* __restrict__ s1,
                                             const int* __restrict__ rank,
                                             const float* __restrict__ ZN,
                                             const float* __restrict__ ZP,
                                             const __hip_bfloat16* __restrict__ Pre,
                                             const __hip_bfloat16* __restrict__ Suf,
                                             float* __restrict__ out) {
    const int tid = threadIdx.x;
    const int lr = tid >> 7, f = tid & 127;
    const int i = blockIdx.x * 2 + lr;
    const int b = i >> 11;

    const float s1v = s1[i];
    const float E1 = expf(s1v);
    const float E2 = expf(LRELU_ALPHA * s1v);
    const int   r  = rank[i];
    const float Z  = E1 * ZP[i] + E2 * ZN[i];
    const size_t o = (size_t)(b * 2049 + r) * 128 + f;
    const float hp = (E1 * __bfloat162float(Suf[o]) + E2 * __bfloat162float(Pre[o])) / Z;
    const float x = hp + LRELU_ALPHA * h[(size_t)i * 128 + f];
    out[(size_t)i * 128 + f] = (x > 0.f) ? x : expm1f(x);
}

// ---------------------------------------------------------------------------
extern "C" void kernel_launch(void* const* d_in, const int* in_sizes, int n_in,
                              void* d_out, int out_size, void* d_ws, size_t ws_size,
                              hipStream_t stream) {
    const float* text = (const float*)d_in[0];
    // d_in[1] = adj : all-ones, unused by the reference math -> never read.
    const float* W = (const float*)d_in[2];
    const float* a = (const float*)d_in[3];
    float* out = (float*)d_out;

    float* p = (float*)d_ws;
    float* h    = p; p += (size_t)M_ * 128;
    float* s1   = p; p += M_;
    float* s2   = p; p += M_;
    float* eN0  = p; p += M_;
    float* eP0  = p; p += M_;
    int*   perm = (int*)p; p += M_;
    float* eNs  = p; p += M_;
    float* ePs  = p; p += M_;
    int*   rank = (int*)p; p += M_;
    float* ZN   = p; p += M_;
    float* ZP   = p; p += M_;
    float* segN = p; p += B_ * NSEG * 128;
    float* segP = p; p += B_ * NSEG * 128;
    __hip_bfloat16* Pre = (__hip_bfloat16*)p; p += (size_t)B_ * 2049 * 128 / 2;
    __hip_bfloat16* Suf = (__hip_bfloat16*)p; p += (size_t)B_ * 2049 * 128 / 2;

    hipLaunchKernelGGL(k_gemm,   dim3(M_ / 64),       dim3(256), 0, stream,
                       text, W, a, h, s1, s2, eN0, eP0);
    hipLaunchKernelGGL(k_rank,   dim3(B_ * 32),       dim3(512), 0, stream,
                       s2, eN0, eP0, s1, perm, eNs, ePs, rank, ZN, ZP);
    hipLaunchKernelGGL(k_segsum, dim3(B_ * NSEG),     dim3(128), 0, stream,
                       h, perm, eNs, ePs, segN, segP);
    hipLaunchKernelGGL(k_prefix, dim3(B_ * NSEG * 2), dim3(128), 0, stream,
                       h, perm, eNs, ePs, segN, segP, Pre, Suf);
    hipLaunchKernelGGL(k_out,    dim3(M_ / 2),        dim3(256), 0, stream,
                       h, s1, rank, ZN, ZP, Pre, Suf, out);
}